// Round 1
// baseline (84.549 us; speedup 1.0000x reference)
//
#include <hip/hip_runtime.h>

// B=8, D=256, DIM=128
// out[b,j,k] = sum_m v[m] * tanh(A[b,j,m] + C[b,k,m]),  A = X@W1^T, C = X@W2^T
//
// Kernel 1: A' = 2*log2(e) * (X @ W1^T), C' = 2*log2(e) * (X @ W2^T) -> d_ws
// Kernel 2: tanh(x) = 1 - 2/(exp2(x') + 1) with x' = A'+C'; out = S - 2*sum v*r

#define TWO_LOG2E 2.88539008177792681472f
#define NROW 2048           // B*D
#define AC_HALF (8*256*128) // 262144 floats per matrix

__global__ __launch_bounds__(256) void pp_proj_kernel(
    const float* __restrict__ X, const float* __restrict__ W1,
    const float* __restrict__ W2, float* __restrict__ AC)
{
    __shared__ float Xs[4 * 128];
    const int tid = threadIdx.x;
    const int r0  = blockIdx.x * 4;          // global row in [0,2048)

    if (tid < 128) {
        *reinterpret_cast<float4*>(Xs + tid * 4) =
            *reinterpret_cast<const float4*>(X + r0 * 128 + tid * 4);
    }
    __syncthreads();

    const int sub = tid >> 7;                // 0 -> A/W1, 1 -> C/W2
    const int m   = tid & 127;
    const float* __restrict__ Wrow = (sub ? W2 : W1) + m * 128;

    float acc[4] = {0.f, 0.f, 0.f, 0.f};
    #pragma unroll 8
    for (int k4 = 0; k4 < 32; ++k4) {
        const float4 w = *reinterpret_cast<const float4*>(Wrow + k4 * 4);
        #pragma unroll
        for (int r = 0; r < 4; ++r) {
            const float4 x = *reinterpret_cast<const float4*>(Xs + r * 128 + k4 * 4);
            acc[r] = fmaf(w.x, x.x, acc[r]);
            acc[r] = fmaf(w.y, x.y, acc[r]);
            acc[r] = fmaf(w.z, x.z, acc[r]);
            acc[r] = fmaf(w.w, x.w, acc[r]);
        }
    }

    float* dst = AC + sub * AC_HALF + r0 * 128 + m;
    #pragma unroll
    for (int r = 0; r < 4; ++r)
        dst[r * 128] = acc[r] * TWO_LOG2E;
}

__device__ __forceinline__ void tanh_acc(float a, float c, float vm, float& acc)
{
    // a,c pre-scaled by 2*log2(e): exp2(a+c) == exp(2*(A+C))
    const float e = __builtin_amdgcn_exp2f(a + c);
    const float r = __builtin_amdgcn_rcpf(e + 1.0f);
    acc = fmaf(vm, r, acc);                  // tanh = 1 - 2r; folded at epilogue
}

__global__ __launch_bounds__(256) void pp_pair_kernel(
    const float* __restrict__ AC, const float* __restrict__ v,
    float* __restrict__ out)
{
    __shared__ float As[32 * 132];           // +4 pad per row: 16B-aligned, 2-way banks
    __shared__ float Cs[32 * 132];
    __shared__ float Vs[128];

    const int tid = threadIdx.x;
    const int bid = blockIdx.x;              // 0..511
    const int b   = bid >> 6;
    const int jt  = (bid >> 3) & 7;
    const int kt  = bid & 7;

    const float* __restrict__ Ap = AC + b * 32768 + jt * 32 * 128;
    const float* __restrict__ Cp = AC + AC_HALF + b * 32768 + kt * 32 * 128;

    #pragma unroll
    for (int i = 0; i < 4; ++i) {
        const int idx = i * 256 + tid;       // 0..1023 float4s
        const int row = idx >> 5, c4 = idx & 31;
        *reinterpret_cast<float4*>(&As[row * 132 + c4 * 4]) =
            *reinterpret_cast<const float4*>(Ap + idx * 4);
        *reinterpret_cast<float4*>(&Cs[row * 132 + c4 * 4]) =
            *reinterpret_cast<const float4*>(Cp + idx * 4);
    }
    if (tid < 32)
        *reinterpret_cast<float4*>(&Vs[tid * 4]) =
            *reinterpret_cast<const float4*>(v + tid * 4);
    __syncthreads();

    // wave-level 8x8 lane layout -> 16 j-rows x 16 k-rows per wave (2-way banks)
    const int w  = tid >> 6, l = tid & 63;
    const int jr = ((w >> 1) << 4) + ((l >> 3) << 1);   // even, 0..30
    const int kr = ((w & 1) << 4) + ((l & 7) << 1);

    const float* __restrict__ A0 = &As[jr * 132];
    const float* __restrict__ A1 = A0 + 132;
    const float* __restrict__ C0 = &Cs[kr * 132];
    const float* __restrict__ C1 = C0 + 132;

    float acc00 = 0.f, acc01 = 0.f, acc10 = 0.f, acc11 = 0.f, accS = 0.f;

    #pragma unroll 4
    for (int m4 = 0; m4 < 32; ++m4) {
        const float4 a0 = *reinterpret_cast<const float4*>(A0 + m4 * 4);
        const float4 a1 = *reinterpret_cast<const float4*>(A1 + m4 * 4);
        const float4 c0 = *reinterpret_cast<const float4*>(C0 + m4 * 4);
        const float4 c1 = *reinterpret_cast<const float4*>(C1 + m4 * 4);
        const float4 vv = *reinterpret_cast<const float4*>(Vs + m4 * 4);

        accS += vv.x + vv.y + vv.z + vv.w;

        tanh_acc(a0.x, c0.x, vv.x, acc00);
        tanh_acc(a0.y, c0.y, vv.y, acc00);
        tanh_acc(a0.z, c0.z, vv.z, acc00);
        tanh_acc(a0.w, c0.w, vv.w, acc00);

        tanh_acc(a0.x, c1.x, vv.x, acc01);
        tanh_acc(a0.y, c1.y, vv.y, acc01);
        tanh_acc(a0.z, c1.z, vv.z, acc01);
        tanh_acc(a0.w, c1.w, vv.w, acc01);

        tanh_acc(a1.x, c0.x, vv.x, acc10);
        tanh_acc(a1.y, c0.y, vv.y, acc10);
        tanh_acc(a1.z, c0.z, vv.z, acc10);
        tanh_acc(a1.w, c0.w, vv.w, acc10);

        tanh_acc(a1.x, c1.x, vv.x, acc11);
        tanh_acc(a1.y, c1.y, vv.y, acc11);
        tanh_acc(a1.z, c1.z, vv.z, acc11);
        tanh_acc(a1.w, c1.w, vv.w, acc11);
    }

    float* orow = out + b * 65536 + (jt * 32 + jr) * 256 + kt * 32 + kr;
    const float2 r0 = {fmaf(-2.f, acc00, accS), fmaf(-2.f, acc01, accS)};
    const float2 r1 = {fmaf(-2.f, acc10, accS), fmaf(-2.f, acc11, accS)};
    *reinterpret_cast<float2*>(orow)       = r0;
    *reinterpret_cast<float2*>(orow + 256) = r1;
}

extern "C" void kernel_launch(void* const* d_in, const int* in_sizes, int n_in,
                              void* d_out, int out_size, void* d_ws, size_t ws_size,
                              hipStream_t stream)
{
    const float* X  = (const float*)d_in[0];
    const float* W1 = (const float*)d_in[1];
    const float* W2 = (const float*)d_in[2];
    const float* v  = (const float*)d_in[3];
    float* out = (float*)d_out;
    float* AC  = (float*)d_ws;               // needs 2*262144*4 = 2 MB

    pp_proj_kernel<<<NROW / 4, 256, 0, stream>>>(X, W1, W2, AC);
    pp_pair_kernel<<<512, 256, 0, stream>>>(AC, v, out);
}

// Round 2
// 84.149 us; speedup vs baseline: 1.0048x; 1.0048x over previous
//
#include <hip/hip_runtime.h>

// B=8, D=256, DIM=128
// out[b,j,k] = sum_m v[m] * tanh(A[b,j,m] + C[b,k,m]),  A = X@W1^T, C = X@W2^T
//
// Kernel 1: A' = 2*log2(e) * (X @ W1^T), C' = 2*log2(e) * (X @ W2^T) -> d_ws
// Kernel 2: tanh(x) = 1 - 2/(exp2(x') + 1) with x' = A'+C'; out = S - 2*sum v*r

#define TWO_LOG2E 2.88539008177792681472f
#define NROW 2048           // B*D
#define AC_HALF (8*256*128) // 262144 floats per matrix

__global__ __launch_bounds__(256) void pp_proj_kernel(
    const float* __restrict__ X, const float* __restrict__ W1,
    const float* __restrict__ W2, float* __restrict__ AC)
{
    __shared__ float Xs[4 * 128];
    const int tid = threadIdx.x;
    const int r0  = blockIdx.x * 4;          // global row in [0,2048)

    if (tid < 128) {
        *reinterpret_cast<float4*>(Xs + tid * 4) =
            *reinterpret_cast<const float4*>(X + r0 * 128 + tid * 4);
    }
    __syncthreads();

    const int sub = tid >> 7;                // 0 -> A/W1, 1 -> C/W2
    const int m   = tid & 127;
    const float* __restrict__ Wrow = (sub ? W2 : W1) + m * 128;

    float acc[4] = {0.f, 0.f, 0.f, 0.f};
    #pragma unroll 8
    for (int k4 = 0; k4 < 32; ++k4) {
        const float4 w = *reinterpret_cast<const float4*>(Wrow + k4 * 4);
        #pragma unroll
        for (int r = 0; r < 4; ++r) {
            const float4 x = *reinterpret_cast<const float4*>(Xs + r * 128 + k4 * 4);
            acc[r] = fmaf(w.x, x.x, acc[r]);
            acc[r] = fmaf(w.y, x.y, acc[r]);
            acc[r] = fmaf(w.z, x.z, acc[r]);
            acc[r] = fmaf(w.w, x.w, acc[r]);
        }
    }

    float* dst = AC + sub * AC_HALF + r0 * 128 + m;
    #pragma unroll
    for (int r = 0; r < 4; ++r)
        dst[r * 128] = acc[r] * TWO_LOG2E;
}

__device__ __forceinline__ void tanh_acc(float a, float c, float vm, float& acc)
{
    // a,c pre-scaled by 2*log2(e): exp2(a+c) == exp(2*(A+C))
    const float e = __builtin_amdgcn_exp2f(a + c);
    const float r = __builtin_amdgcn_rcpf(e + 1.0f);
    acc = fmaf(vm, r, acc);                  // tanh = 1 - 2r; folded at epilogue
}

__global__ __launch_bounds__(256, 2) void pp_pair_kernel(
    const float* __restrict__ AC, const float* __restrict__ v,
    float* __restrict__ out)
{
    __shared__ float As[32 * 132];           // +4 pad per row: 16B-aligned, 2-way banks
    __shared__ float Cs[32 * 132];
    __shared__ float Vs[128];

    const int tid = threadIdx.x;
    const int bid = blockIdx.x;              // 0..511
    const int b   = bid >> 6;
    const int jt  = (bid >> 3) & 7;
    const int kt  = bid & 7;

    const float* __restrict__ Ap = AC + b * 32768 + jt * 32 * 128;
    const float* __restrict__ Cp = AC + AC_HALF + b * 32768 + kt * 32 * 128;

    #pragma unroll
    for (int i = 0; i < 4; ++i) {
        const int idx = i * 256 + tid;       // 0..1023 float4s
        const int row = idx >> 5, c4 = idx & 31;
        *reinterpret_cast<float4*>(&As[row * 132 + c4 * 4]) =
            *reinterpret_cast<const float4*>(Ap + idx * 4);
        *reinterpret_cast<float4*>(&Cs[row * 132 + c4 * 4]) =
            *reinterpret_cast<const float4*>(Cp + idx * 4);
    }
    if (tid < 32)
        *reinterpret_cast<float4*>(&Vs[tid * 4]) =
            *reinterpret_cast<const float4*>(v + tid * 4);
    __syncthreads();

    // wave-level 8x8 lane layout -> 16 j-rows x 16 k-rows per wave (2-way banks max)
    const int w  = tid >> 6, l = tid & 63;
    const int jr = ((w >> 1) << 4) + ((l >> 3) << 1);   // even, 0..30
    const int kr = ((w & 1) << 4) + ((l & 7) << 1);

    const float* __restrict__ A0 = &As[jr * 132];
    const float* __restrict__ A1 = A0 + 132;
    const float* __restrict__ C0 = &Cs[kr * 132];
    const float* __restrict__ C1 = C0 + 132;

    // sum(v) once, outside the hot loop (broadcast reads, no conflict)
    float sumv = 0.f;
    #pragma unroll
    for (int i = 0; i < 32; ++i) {
        const float4 vv = *reinterpret_cast<const float4*>(Vs + i * 4);
        sumv += (vv.x + vv.y) + (vv.z + vv.w);
    }

    float acc00 = 0.f, acc01 = 0.f, acc10 = 0.f, acc11 = 0.f;

    #pragma unroll 2
    for (int m4 = 0; m4 < 32; ++m4) {
        const float4 a0 = *reinterpret_cast<const float4*>(A0 + m4 * 4);
        const float4 a1 = *reinterpret_cast<const float4*>(A1 + m4 * 4);
        const float4 c0 = *reinterpret_cast<const float4*>(C0 + m4 * 4);
        const float4 c1 = *reinterpret_cast<const float4*>(C1 + m4 * 4);
        const float4 vv = *reinterpret_cast<const float4*>(Vs + m4 * 4);

        tanh_acc(a0.x, c0.x, vv.x, acc00);
        tanh_acc(a0.y, c0.y, vv.y, acc00);
        tanh_acc(a0.z, c0.z, vv.z, acc00);
        tanh_acc(a0.w, c0.w, vv.w, acc00);

        tanh_acc(a0.x, c1.x, vv.x, acc01);
        tanh_acc(a0.y, c1.y, vv.y, acc01);
        tanh_acc(a0.z, c1.z, vv.z, acc01);
        tanh_acc(a0.w, c1.w, vv.w, acc01);

        tanh_acc(a1.x, c0.x, vv.x, acc10);
        tanh_acc(a1.y, c0.y, vv.y, acc10);
        tanh_acc(a1.z, c0.z, vv.z, acc10);
        tanh_acc(a1.w, c0.w, vv.w, acc10);

        tanh_acc(a1.x, c1.x, vv.x, acc11);
        tanh_acc(a1.y, c1.y, vv.y, acc11);
        tanh_acc(a1.z, c1.z, vv.z, acc11);
        tanh_acc(a1.w, c1.w, vv.w, acc11);
    }

    float* orow = out + b * 65536 + (jt * 32 + jr) * 256 + kt * 32 + kr;
    const float2 r0 = {fmaf(-2.f, acc00, sumv), fmaf(-2.f, acc01, sumv)};
    const float2 r1 = {fmaf(-2.f, acc10, sumv), fmaf(-2.f, acc11, sumv)};
    *reinterpret_cast<float2*>(orow)       = r0;
    *reinterpret_cast<float2*>(orow + 256) = r1;
}

extern "C" void kernel_launch(void* const* d_in, const int* in_sizes, int n_in,
                              void* d_out, int out_size, void* d_ws, size_t ws_size,
                              hipStream_t stream)
{
    const float* X  = (const float*)d_in[0];
    const float* W1 = (const float*)d_in[1];
    const float* W2 = (const float*)d_in[2];
    const float* v  = (const float*)d_in[3];
    float* out = (float*)d_out;
    float* AC  = (float*)d_ws;               // needs 2*262144*4 = 2 MB

    pp_proj_kernel<<<NROW / 4, 256, 0, stream>>>(X, W1, W2, AC);
    pp_pair_kernel<<<512, 256, 0, stream>>>(AC, v, out);
}